// Round 1
// baseline (1785.275 us; speedup 1.0000x reference)
//
#include <hip/hip_runtime.h>
#include <stdint.h>

// Problem constants (x: (2,21,256,256) f32, image: (2,3,256,256) f32, bilateral d=5)
#define BB   2
#define CC   21
#define CP   24              // padded channel stride (float4-aligned)
#define NPT  (BB*256*256)    // 131072 points
#define DP1  6
#define NV   (NPT*DP1)       // 786432 point-vertex pairs (max unique keys)
#define TS   (1u<<21)        // hash slots (max load 37.5%)
#define TMASK (TS-1)
#define EMPTYK 0xFFFFFFFFFFFFFFFFULL

__device__ __forceinline__ uint64_t hmix(uint64_t x){
  x ^= x >> 33; x *= 0xff51afd7ed558ccdULL;
  x ^= x >> 33; x *= 0xc4ceb9fe1a85ec53ULL;
  x ^= x >> 33; return x;
}

__device__ __forceinline__ int hlookup(const unsigned long long* __restrict__ hk,
                                       const int* __restrict__ sidx, uint64_t key){
  uint32_t h = (uint32_t)hmix(key) & TMASK;
  for (uint32_t p = 0; p < TS; ++p){
    unsigned long long k = hk[h];
    if (k == (unsigned long long)key) return sidx[h];
    if (k == EMPTYK) return -1;
    h = (h + 1) & TMASK;
  }
  return -1;
}

// K1: per-point lattice math + hash insert (key-only)
__global__ __launch_bounds__(256) void k_build(const float* __restrict__ img,
      unsigned long long* __restrict__ hk,
      unsigned long long* __restrict__ pkeys,
      float* __restrict__ pbary){
  int n = blockIdx.x*256 + threadIdx.x;
  if (n >= NPT) return;
  int b = n >> 16, pix = n & 65535;
  int y = pix >> 8, x = pix & 255;
  // scale[j] = sqrt(2/3)*6 / sqrt((j+1)(j+2)), as float32 (numpy f64 -> f32)
  const float sc0 = 3.4641016151377544f, sc1 = 2.0f, sc2 = 1.4142135623730951f,
              sc3 = 1.0954451150103321f, sc4 = 0.8944271909999159f;
  size_t ib = ((size_t)b*3) << 16;
  float f0 = ((float)x / 80.0f) * sc0;                      // xs / THETA_ALPHA
  float f1 = ((float)y / 80.0f) * sc1;                      // ys / THETA_ALPHA
  float f2 = (img[ib + pix]          / 13.0f) * sc2;        // R / THETA_BETA
  float f3 = (img[ib + 65536 + pix]  / 13.0f) * sc3;        // G
  float f4 = (img[ib + 131072 + pix] / 13.0f) * sc4;        // B
  // elevate: E rows [1,1,1,1,1],[-1,1,1,1,1],[0,-2,1,1,1],[0,0,-3,1,1],[0,0,0,-4,1],[0,0,0,0,-5]
  float E[6];
  {
    float s4 = f4;
    E[5] = -5.0f*f4;
    E[4] = -4.0f*f3 + s4;
    float s3 = f3 + s4;
    E[3] = -3.0f*f2 + s3;
    float s2 = f2 + s3;
    E[2] = -2.0f*f1 + s2;
    float s1 = f1 + s2;
    E[1] = -f0 + s1;
    E[0] =  f0 + s1;
  }
  float rem0[6], di[6]; int rk[6];
  float ssf = 0.f;
  #pragma unroll
  for (int i=0;i<6;i++){
    float v  = E[i] / 6.0f;
    float up = ceilf(v)*6.0f, dn = floorf(v)*6.0f;
    float r0 = (up - E[i] < E[i] - dn) ? up : dn;
    rem0[i] = r0; di[i] = E[i] - r0; ssf += r0;     // di from PRE-wrap rem0
  }
  int ssum = (int)rintf(ssf / 6.0f);                 // exact: rem0 are multiples of 6
  #pragma unroll
  for (int i=0;i<6;i++){
    int c = ssum;
    #pragma unroll
    for (int k=0;k<6;k++){
      if (k==i) continue;
      bool t = (k>i) ? (di[i] < di[k]) : (di[i] <= di[k]);
      c += t ? 1 : 0;
    }
    rk[i] = c;
  }
  #pragma unroll
  for (int i=0;i<6;i++){
    if      (rk[i] < 0){ rk[i] += 6; rem0[i] += 6.0f; }
    else if (rk[i] > 5){ rk[i] -= 6; rem0[i] -= 6.0f; }
  }
  // barycentric: bar[5-rk] += t; bar[6-rk] -= t  (unrolled to keep in registers)
  float bar[7] = {0,0,0,0,0,0,0};
  #pragma unroll
  for (int i=0;i<6;i++){
    float t = (E[i] - rem0[i]) / 6.0f;               // t from POST-wrap rem0
    #pragma unroll
    for (int j=0;j<7;j++){
      bar[j] += ((5-rk[i])==j) ? t : 0.0f;
      bar[j] -= ((6-rk[i])==j) ? t : 0.0f;
    }
  }
  float w0 = bar[0] + 1.0f + bar[6];
  int ri[5];
  #pragma unroll
  for (int i=0;i<5;i++) ri[i] = (int)rintf(rem0[i]);
  uint64_t bbit = ((uint64_t)b) << 60;
  #pragma unroll
  for (int r=0;r<6;r++){
    uint64_t key = bbit;
    #pragma unroll
    for (int i=0;i<5;i++){
      int k = ri[i] + r - ((rk[i] > 5-r) ? 6 : 0);
      key |= ((uint64_t)(uint32_t)(k + 2048)) << (12*i);
    }
    pkeys[n*6+r] = key;
    pbary[n*6+r] = (r==0) ? w0 : bar[r];
    uint32_t h = (uint32_t)hmix(key) & TMASK;
    for (uint32_t p = 0; p < TS; ++p){
      unsigned long long prev = atomicCAS(&hk[h], EMPTYK, (unsigned long long)key);
      if (prev == EMPTYK || prev == (unsigned long long)key) break;
      h = (h + 1) & TMASK;
    }
  }
}

// K2: assign compact indices to occupied hash slots
__global__ __launch_bounds__(256) void k_compact(const unsigned long long* __restrict__ hk,
      int* __restrict__ sidx, unsigned long long* __restrict__ latkeys, int* __restrict__ counter){
  uint32_t s = blockIdx.x*256 + threadIdx.x;
  unsigned long long k = hk[s];
  if (k != EMPTYK){
    int i = atomicAdd(counter, 1);
    sidx[s] = i;
    latkeys[i] = k;
  }
}

// K3: per (point,vertex) -> compact lattice index
__global__ __launch_bounds__(256) void k_find(const unsigned long long* __restrict__ hk,
      const int* __restrict__ sidx, const unsigned long long* __restrict__ pkeys,
      int* __restrict__ pidx){
  int t = blockIdx.x*256 + threadIdx.x;
  if (t >= NV) return;
  int i = hlookup(hk, sidx, pkeys[t]);
  pidx[t] = (i >= 0) ? i : 0;   // always found (inserted in K1)
}

// K4: splat — scatter-add bary * vals into lattice
__global__ __launch_bounds__(256) void k_splat(const float* __restrict__ xin,
      const int* __restrict__ pidx, const float* __restrict__ pbary, float* __restrict__ lat){
  int t = blockIdx.x*256 + threadIdx.x;
  if (t >= NV) return;
  int n = t / 6;
  int idx = pidx[t]; float w = pbary[t];
  int b = n >> 16, pix = n & 65535;
  const float* xb = xin + (((size_t)b*CC) << 16) + pix;
  float* dstp = lat + (size_t)idx*CP;
  #pragma unroll
  for (int c=0;c<CC;c++) atomicAdd(&dstp[c], w * xb[(size_t)c << 16]);
}

// K5: one blur direction: dst[m] = src[m] + 0.5*(src[n1] + src[n2]), missing -> 0
__global__ __launch_bounds__(256) void k_blur(const unsigned long long* __restrict__ hk,
      const int* __restrict__ sidx, const unsigned long long* __restrict__ latkeys,
      const int* __restrict__ counter, const float* __restrict__ src, float* __restrict__ dst,
      unsigned long long delta){
  int m = blockIdx.x*256 + threadIdx.x;
  if (m >= *counter) return;
  uint64_t key = (uint64_t)latkeys[m];
  int i1 = hlookup(hk, sidx, key + (uint64_t)delta);
  int i2 = hlookup(hk, sidx, key - (uint64_t)delta);
  const float4* a = (const float4*)(src + (size_t)m*CP);
  const float4* u = (i1 >= 0) ? (const float4*)(src + (size_t)i1*CP) : nullptr;
  const float4* v = (i2 >= 0) ? (const float4*)(src + (size_t)i2*CP) : nullptr;
  float4* o = (float4*)(dst + (size_t)m*CP);
  #pragma unroll
  for (int q=0;q<CP/4;q++){
    float4 av = a[q];
    float4 uv = u ? u[q] : make_float4(0.f,0.f,0.f,0.f);
    float4 vv = v ? v[q] : make_float4(0.f,0.f,0.f,0.f);
    float4 r;
    r.x = av.x + 0.5f*(uv.x + vv.x);
    r.y = av.y + 0.5f*(uv.y + vv.y);
    r.z = av.z + 0.5f*(uv.z + vv.z);
    r.w = av.w + 0.5f*(uv.w + vv.w);
    o[q] = r;
  }
}

// K6: slice — out[b,c,y,x] = alpha * sum_r bary[r] * lat[idx[r]][c]
__global__ __launch_bounds__(256) void k_slice(const float* __restrict__ lat,
      const int* __restrict__ pidx, const float* __restrict__ pbary, float* __restrict__ out){
  int n = blockIdx.x*256 + threadIdx.x;
  if (n >= NPT) return;
  float acc[CC];
  #pragma unroll
  for (int c=0;c<CC;c++) acc[c] = 0.f;
  #pragma unroll
  for (int r=0;r<6;r++){
    int idx = pidx[n*6+r]; float w = pbary[n*6+r];
    const float* L = lat + (size_t)idx*CP;
    #pragma unroll
    for (int c=0;c<CC;c++) acc[c] = fmaf(w, L[c], acc[c]);
  }
  int b = n >> 16, pix = n & 65535;
  float* ob = out + (((size_t)b*CC) << 16) + pix;
  const float alpha = 0.9696969696969697f;  // 1/(1+2^-5) = 32/33
  #pragma unroll
  for (int c=0;c<CC;c++) ob[(size_t)c << 16] = alpha * acc[c];
}

extern "C" void kernel_launch(void* const* d_in, const int* in_sizes, int n_in,
                              void* d_out, int out_size, void* d_ws, size_t ws_size,
                              hipStream_t stream){
  const float* xin = (const float*)d_in[0];   // (2,21,256,256)
  const float* img = (const float*)d_in[1];   // (2,3,256,256)
  float* out = (float*)d_out;                 // (2,21,256,256)

  // workspace carve (each region 256B-aligned); total ~196 MB
  char* p = (char*)d_ws;
  auto carve = [&](size_t bytes)->char*{
    char* r = p; p += (bytes + 255) & ~(size_t)255; return r;
  };
  unsigned long long* hk      = (unsigned long long*)carve((size_t)TS*8);   // 16.8 MB
  int*                sidx    = (int*)               carve((size_t)TS*4);   //  8.4 MB
  unsigned long long* latkeys = (unsigned long long*)carve((size_t)NV*8);   //  6.3 MB
  int*                counter = (int*)               carve(256);
  unsigned long long* pkeys   = (unsigned long long*)carve((size_t)NV*8);   //  6.3 MB
  int*                pidx    = (int*)               carve((size_t)NV*4);   //  3.1 MB
  float*              pbary   = (float*)             carve((size_t)NV*4);   //  3.1 MB
  float*              latA    = (float*)             carve((size_t)NV*CP*4);// 75.5 MB
  float*              latB    = (float*)             carve((size_t)NV*CP*4);// 75.5 MB

  hipMemsetAsync(hk, 0xFF, (size_t)TS*8, stream);
  hipMemsetAsync(counter, 0, 256, stream);
  hipMemsetAsync(latA, 0, (size_t)NV*CP*4, stream);

  k_build  <<<NPT/256, 256, 0, stream>>>(img, hk, pkeys, pbary);
  k_compact<<<TS/256,  256, 0, stream>>>(hk, sidx, latkeys, counter);
  k_find   <<<NV/256,  256, 0, stream>>>(hk, sidx, pkeys, pidx);
  k_splat  <<<NV/256,  256, 0, stream>>>(xin, pidx, pbary, latA);

  // blur deltas: off = ones(6), off[j] = -5; packed coords are fields i=0..4.
  // delta_j = sum_{i<5} 4096^i - 6*4096^j (j<5); j==5 only touches the unpacked coord.
  const long long S5 = (1LL<<48)+(1LL<<36)+(1LL<<24)+(1LL<<12)+1LL;
  float* src = latA; float* dst = latB;
  for (int j=0;j<6;j++){
    long long delta = (j<5) ? (S5 - (6LL << (12*j))) : S5;
    k_blur<<<NV/256, 256, 0, stream>>>(hk, sidx, latkeys, counter, src, dst,
                                       (unsigned long long)delta);
    float* tmp = src; src = dst; dst = tmp;
  }
  // after 6 swaps src == latA (final)
  k_slice<<<NPT/256, 256, 0, stream>>>(src, pidx, pbary, out);
}

// Round 2
// 1226.893 us; speedup vs baseline: 1.4551x; 1.4551x over previous
//
#include <hip/hip_runtime.h>
#include <stdint.h>

// Problem constants (x: (2,21,256,256) f32, image: (2,3,256,256) f32, bilateral d=5)
#define BB   2
#define CC   21
#define CP   24              // padded channel stride (float4-aligned)
#define NPT  (BB*256*256)    // 131072 points
#define DP1  6
#define NV   (NPT*DP1)       // 786432 point-vertex pairs (max unique keys)
#define TS   (1u<<21)        // hash slots (max load 37.5%)
#define TMASK (TS-1)
#define EMPTYK 0xFFFFFFFFFFFFFFFFULL
#define NBLK (NV/1024)       // 768 scan blocks

__device__ __forceinline__ uint64_t hmix(uint64_t x){
  x ^= x >> 33; x *= 0xff51afd7ed558ccdULL;
  x ^= x >> 33; x *= 0xc4ceb9fe1a85ec53ULL;
  x ^= x >> 33; return x;
}

__device__ __forceinline__ int hlookup(const unsigned long long* __restrict__ hk,
                                       const int* __restrict__ sidx, uint64_t key){
  uint32_t h = (uint32_t)hmix(key) & TMASK;
  for (uint32_t p = 0; p < TS; ++p){
    unsigned long long k = hk[h];
    if (k == (unsigned long long)key) return sidx[h];
    if (k == EMPTYK) return -1;
    h = (h + 1) & TMASK;
  }
  return -1;
}

// K1: per-point lattice math + hash insert (key-only)
__global__ __launch_bounds__(256) void k_build(const float* __restrict__ img,
      unsigned long long* __restrict__ hk,
      unsigned long long* __restrict__ pkeys,
      float* __restrict__ pbary){
  int n = blockIdx.x*256 + threadIdx.x;
  if (n >= NPT) return;
  int b = n >> 16, pix = n & 65535;
  int y = pix >> 8, x = pix & 255;
  // scale[j] = sqrt(2/3)*6 / sqrt((j+1)(j+2)), as float32 (numpy f64 -> f32)
  const float sc0 = 3.4641016151377544f, sc1 = 2.0f, sc2 = 1.4142135623730951f,
              sc3 = 1.0954451150103321f, sc4 = 0.8944271909999159f;
  size_t ib = ((size_t)b*3) << 16;
  float f0 = ((float)x / 80.0f) * sc0;                      // xs / THETA_ALPHA
  float f1 = ((float)y / 80.0f) * sc1;                      // ys / THETA_ALPHA
  float f2 = (img[ib + pix]          / 13.0f) * sc2;        // R / THETA_BETA
  float f3 = (img[ib + 65536 + pix]  / 13.0f) * sc3;        // G
  float f4 = (img[ib + 131072 + pix] / 13.0f) * sc4;        // B
  // elevate: E rows [1,1,1,1,1],[-1,1,1,1,1],[0,-2,1,1,1],[0,0,-3,1,1],[0,0,0,-4,1],[0,0,0,0,-5]
  float E[6];
  {
    float s4 = f4;
    E[5] = -5.0f*f4;
    E[4] = -4.0f*f3 + s4;
    float s3 = f3 + s4;
    E[3] = -3.0f*f2 + s3;
    float s2 = f2 + s3;
    E[2] = -2.0f*f1 + s2;
    float s1 = f1 + s2;
    E[1] = -f0 + s1;
    E[0] =  f0 + s1;
  }
  float rem0[6], di[6]; int rk[6];
  float ssf = 0.f;
  #pragma unroll
  for (int i=0;i<6;i++){
    float v  = E[i] / 6.0f;
    float up = ceilf(v)*6.0f, dn = floorf(v)*6.0f;
    float r0 = (up - E[i] < E[i] - dn) ? up : dn;
    rem0[i] = r0; di[i] = E[i] - r0; ssf += r0;     // di from PRE-wrap rem0
  }
  int ssum = (int)rintf(ssf / 6.0f);                 // exact: rem0 are multiples of 6
  #pragma unroll
  for (int i=0;i<6;i++){
    int c = ssum;
    #pragma unroll
    for (int k=0;k<6;k++){
      if (k==i) continue;
      bool t = (k>i) ? (di[i] < di[k]) : (di[i] <= di[k]);
      c += t ? 1 : 0;
    }
    rk[i] = c;
  }
  #pragma unroll
  for (int i=0;i<6;i++){
    if      (rk[i] < 0){ rk[i] += 6; rem0[i] += 6.0f; }
    else if (rk[i] > 5){ rk[i] -= 6; rem0[i] -= 6.0f; }
  }
  // barycentric: bar[5-rk] += t; bar[6-rk] -= t  (unrolled to keep in registers)
  float bar[7] = {0,0,0,0,0,0,0};
  #pragma unroll
  for (int i=0;i<6;i++){
    float t = (E[i] - rem0[i]) / 6.0f;               // t from POST-wrap rem0
    #pragma unroll
    for (int j=0;j<7;j++){
      bar[j] += ((5-rk[i])==j) ? t : 0.0f;
      bar[j] -= ((6-rk[i])==j) ? t : 0.0f;
    }
  }
  float w0 = bar[0] + 1.0f + bar[6];
  int ri[5];
  #pragma unroll
  for (int i=0;i<5;i++) ri[i] = (int)rintf(rem0[i]);
  uint64_t bbit = ((uint64_t)b) << 60;
  #pragma unroll
  for (int r=0;r<6;r++){
    uint64_t key = bbit;
    #pragma unroll
    for (int i=0;i<5;i++){
      int k = ri[i] + r - ((rk[i] > 5-r) ? 6 : 0);
      key |= ((uint64_t)(uint32_t)(k + 2048)) << (12*i);
    }
    pkeys[n*6+r] = key;
    pbary[n*6+r] = (r==0) ? w0 : bar[r];
    uint32_t h = (uint32_t)hmix(key) & TMASK;
    for (uint32_t p = 0; p < TS; ++p){
      unsigned long long prev = atomicCAS(&hk[h], EMPTYK, (unsigned long long)key);
      if (prev == EMPTYK || prev == (unsigned long long)key) break;
      h = (h + 1) & TMASK;
    }
  }
}

// K2: assign compact indices to occupied hash slots
__global__ __launch_bounds__(256) void k_compact(const unsigned long long* __restrict__ hk,
      int* __restrict__ sidx, unsigned long long* __restrict__ latkeys, int* __restrict__ counter){
  uint32_t s = blockIdx.x*256 + threadIdx.x;
  unsigned long long k = hk[s];
  if (k != EMPTYK){
    int i = atomicAdd(counter, 1);
    sidx[s] = i;
    latkeys[i] = k;
  }
}

// K3: per (point,vertex) -> compact lattice index, + histogram of pairs per vertex
__global__ __launch_bounds__(256) void k_find(const unsigned long long* __restrict__ hk,
      const int* __restrict__ sidx, const unsigned long long* __restrict__ pkeys,
      int* __restrict__ pidx, int* __restrict__ cnt){
  int t = blockIdx.x*256 + threadIdx.x;
  if (t >= NV) return;
  int i = hlookup(hk, sidx, pkeys[t]);
  i = (i >= 0) ? i : 0;   // always found (inserted in K1)
  pidx[t] = i;
  atomicAdd(&cnt[i], 1);
}

// Scan stage 1: per-block (1024) exclusive scan of cnt -> off, block totals -> bsum
__global__ __launch_bounds__(1024) void k_scan1(const int* __restrict__ cnt,
      int* __restrict__ off, int* __restrict__ bsum){
  __shared__ int s[1024];
  int t = threadIdx.x;
  int i = blockIdx.x*1024 + t;
  int v = cnt[i];
  s[t] = v;
  __syncthreads();
  #pragma unroll
  for (int o=1;o<1024;o<<=1){
    int add = (t>=o) ? s[t-o] : 0;
    __syncthreads();
    s[t] += add;
    __syncthreads();
  }
  off[i] = s[t] - v;                 // exclusive within block
  if (t==1023) bsum[blockIdx.x] = s[t];
}

// Scan stage 2: exclusive scan of NBLK block sums (single block)
__global__ __launch_bounds__(1024) void k_scan2(int* __restrict__ bsum){
  __shared__ int s[1024];
  int t = threadIdx.x;
  int v = (t < NBLK) ? bsum[t] : 0;
  s[t] = v;
  __syncthreads();
  #pragma unroll
  for (int o=1;o<1024;o<<=1){
    int add = (t>=o) ? s[t-o] : 0;
    __syncthreads();
    s[t] += add;
    __syncthreads();
  }
  if (t < NBLK) bsum[t] = s[t] - v;
}

// Scan stage 3: add block offsets; also init cursor copy
__global__ __launch_bounds__(1024) void k_scan3(int* __restrict__ off,
      const int* __restrict__ bsum, int* __restrict__ cur){
  int i = blockIdx.x*1024 + threadIdx.x;
  int o = off[i] + bsum[blockIdx.x];
  off[i] = o;
  cur[i] = o;
}

// K4a: scatter pair ids into CSR pairlist (one int atomic per pair)
__global__ __launch_bounds__(256) void k_scatter(const int* __restrict__ pidx,
      int* __restrict__ cur, int* __restrict__ pairlist){
  int t = blockIdx.x*256 + threadIdx.x;
  if (t >= NV) return;
  int idx = pidx[t];
  int pos = atomicAdd(&cur[idx], 1);
  pairlist[pos] = t;
}

// K4b: gather-reduce splat — one thread per lattice point, no float atomics
__global__ __launch_bounds__(256) void k_splat2(const float* __restrict__ xin,
      const int* __restrict__ off, const int* __restrict__ cnt,
      const int* __restrict__ pairlist, const float* __restrict__ pbary,
      const int* __restrict__ counter, float* __restrict__ lat){
  int m = blockIdx.x*256 + threadIdx.x;
  if (m >= *counter) return;
  float acc[CC];
  #pragma unroll
  for (int c=0;c<CC;c++) acc[c] = 0.f;
  int c0 = off[m], k = cnt[m];
  for (int e=c0; e<c0+k; ++e){
    int t = pairlist[e];
    int n = t/6;
    float w = pbary[t];
    int b = n >> 16, pix = n & 65535;
    const float* xb = xin + (((size_t)b*CC) << 16) + pix;
    #pragma unroll
    for (int c=0;c<CC;c++) acc[c] = fmaf(w, xb[(size_t)c << 16], acc[c]);
  }
  float* dstp = lat + (size_t)m*CP;
  #pragma unroll
  for (int c=0;c<CC;c++) dstp[c] = acc[c];
  dstp[21] = 0.f; dstp[22] = 0.f; dstp[23] = 0.f;
}

// K5: one blur direction: dst[m] = src[m] + 0.5*(src[n1] + src[n2]), missing -> 0
__global__ __launch_bounds__(256) void k_blur(const unsigned long long* __restrict__ hk,
      const int* __restrict__ sidx, const unsigned long long* __restrict__ latkeys,
      const int* __restrict__ counter, const float* __restrict__ src, float* __restrict__ dst,
      unsigned long long delta){
  int m = blockIdx.x*256 + threadIdx.x;
  if (m >= *counter) return;
  uint64_t key = (uint64_t)latkeys[m];
  int i1 = hlookup(hk, sidx, key + (uint64_t)delta);
  int i2 = hlookup(hk, sidx, key - (uint64_t)delta);
  const float4* a = (const float4*)(src + (size_t)m*CP);
  const float4* u = (i1 >= 0) ? (const float4*)(src + (size_t)i1*CP) : nullptr;
  const float4* v = (i2 >= 0) ? (const float4*)(src + (size_t)i2*CP) : nullptr;
  float4* o = (float4*)(dst + (size_t)m*CP);
  #pragma unroll
  for (int q=0;q<CP/4;q++){
    float4 av = a[q];
    float4 uv = u ? u[q] : make_float4(0.f,0.f,0.f,0.f);
    float4 vv = v ? v[q] : make_float4(0.f,0.f,0.f,0.f);
    float4 r;
    r.x = av.x + 0.5f*(uv.x + vv.x);
    r.y = av.y + 0.5f*(uv.y + vv.y);
    r.z = av.z + 0.5f*(uv.z + vv.z);
    r.w = av.w + 0.5f*(uv.w + vv.w);
    o[q] = r;
  }
}

// K6: slice — out[b,c,y,x] = alpha * sum_r bary[r] * lat[idx[r]][c]
__global__ __launch_bounds__(256) void k_slice(const float* __restrict__ lat,
      const int* __restrict__ pidx, const float* __restrict__ pbary, float* __restrict__ out){
  int n = blockIdx.x*256 + threadIdx.x;
  if (n >= NPT) return;
  float acc[CC];
  #pragma unroll
  for (int c=0;c<CC;c++) acc[c] = 0.f;
  #pragma unroll
  for (int r=0;r<6;r++){
    int idx = pidx[n*6+r]; float w = pbary[n*6+r];
    const float* L = lat + (size_t)idx*CP;
    #pragma unroll
    for (int c=0;c<CC;c++) acc[c] = fmaf(w, L[c], acc[c]);
  }
  int b = n >> 16, pix = n & 65535;
  float* ob = out + (((size_t)b*CC) << 16) + pix;
  const float alpha = 0.9696969696969697f;  // 1/(1+2^-5) = 32/33
  #pragma unroll
  for (int c=0;c<CC;c++) ob[(size_t)c << 16] = alpha * acc[c];
}

extern "C" void kernel_launch(void* const* d_in, const int* in_sizes, int n_in,
                              void* d_out, int out_size, void* d_ws, size_t ws_size,
                              hipStream_t stream){
  const float* xin = (const float*)d_in[0];   // (2,21,256,256)
  const float* img = (const float*)d_in[1];   // (2,3,256,256)
  float* out = (float*)d_out;                 // (2,21,256,256)

  // workspace carve (each region 256B-aligned)
  char* p = (char*)d_ws;
  auto carve = [&](size_t bytes)->char*{
    char* r = p; p += (bytes + 255) & ~(size_t)255; return r;
  };
  unsigned long long* hk      = (unsigned long long*)carve((size_t)TS*8);   // 16.8 MB
  int*                sidx    = (int*)               carve((size_t)TS*4);   //  8.4 MB
  unsigned long long* latkeys = (unsigned long long*)carve((size_t)NV*8);   //  6.3 MB
  int*                counter = (int*)               carve(256);
  unsigned long long* pkeys   = (unsigned long long*)carve((size_t)NV*8);   //  6.3 MB
  int*                pidx    = (int*)               carve((size_t)NV*4);   //  3.1 MB
  float*              pbary   = (float*)             carve((size_t)NV*4);   //  3.1 MB
  int*                cnt     = (int*)               carve((size_t)NV*4);   //  3.1 MB
  int*                off     = (int*)               carve((size_t)NV*4);   //  3.1 MB
  int*                cur     = (int*)               carve((size_t)NV*4);   //  3.1 MB
  int*                plist   = (int*)               carve((size_t)NV*4);   //  3.1 MB
  int*                bsum    = (int*)               carve((size_t)NBLK*4); //  3 KB
  float*              latA    = (float*)             carve((size_t)NV*CP*4);// 75.5 MB
  float*              latB    = (float*)             carve((size_t)NV*CP*4);// 75.5 MB

  hipMemsetAsync(hk, 0xFF, (size_t)TS*8, stream);
  hipMemsetAsync(counter, 0, 256, stream);
  hipMemsetAsync(cnt, 0, (size_t)NV*4, stream);

  k_build  <<<NPT/256, 256, 0, stream>>>(img, hk, pkeys, pbary);
  k_compact<<<TS/256,  256, 0, stream>>>(hk, sidx, latkeys, counter);
  k_find   <<<NV/256,  256, 0, stream>>>(hk, sidx, pkeys, pidx, cnt);
  k_scan1  <<<NBLK,   1024, 0, stream>>>(cnt, off, bsum);
  k_scan2  <<<1,      1024, 0, stream>>>(bsum);
  k_scan3  <<<NBLK,   1024, 0, stream>>>(off, bsum, cur);
  k_scatter<<<NV/256,  256, 0, stream>>>(pidx, cur, plist);
  k_splat2 <<<NV/256,  256, 0, stream>>>(xin, off, cnt, plist, pbary, counter, latA);

  // blur deltas: off = ones(6), off[j] = -5; packed coords are fields i=0..4.
  // delta_j = sum_{i<5} 4096^i - 6*4096^j (j<5); j==5 only touches the unpacked coord.
  const long long S5 = (1LL<<48)+(1LL<<36)+(1LL<<24)+(1LL<<12)+1LL;
  float* src = latA; float* dst = latB;
  for (int j=0;j<6;j++){
    long long delta = (j<5) ? (S5 - (6LL << (12*j))) : S5;
    k_blur<<<NV/256, 256, 0, stream>>>(hk, sidx, latkeys, counter, src, dst,
                                       (unsigned long long)delta);
    float* tmp = src; src = dst; dst = tmp;
  }
  // after 6 swaps src == latA (final)
  k_slice<<<NPT/256, 256, 0, stream>>>(src, pidx, pbary, out);
}

// Round 3
// 923.800 us; speedup vs baseline: 1.9325x; 1.3281x over previous
//
#include <hip/hip_runtime.h>
#include <stdint.h>

// Problem constants (x: (2,21,256,256) f32, image: (2,3,256,256) f32, bilateral d=5)
#define BB   2
#define CC   21
#define CP   24              // padded channel stride (float4-aligned)
#define NPT  (BB*256*256)    // 131072 points
#define DP1  6
#define NV   (NPT*DP1)       // 786432 point-vertex pairs (max unique keys)
#define TS   (1u<<21)        // hash slots (max load 37.5%)
#define TMASK (TS-1)
#define EMPTYK 0xFFFFFFFFFFFFFFFFULL
#define NBLK (NV/1024)       // 768 scan blocks

__device__ __forceinline__ uint64_t hmix(uint64_t x){
  x ^= x >> 33; x *= 0xff51afd7ed558ccdULL;
  x ^= x >> 33; x *= 0xc4ceb9fe1a85ec53ULL;
  x ^= x >> 33; return x;
}

__device__ __forceinline__ int hlookup(const unsigned long long* __restrict__ hk,
                                       const int* __restrict__ sidx, uint64_t key){
  uint32_t h = (uint32_t)hmix(key) & TMASK;
  for (uint32_t p = 0; p < TS; ++p){
    unsigned long long k = hk[h];
    if (k == (unsigned long long)key) return sidx[h];
    if (k == EMPTYK) return -1;
    h = (h + 1) & TMASK;
  }
  return -1;
}

// K1: per-point lattice math + hash insert (key-only)
__global__ __launch_bounds__(256) void k_build(const float* __restrict__ img,
      unsigned long long* __restrict__ hk,
      unsigned long long* __restrict__ pkeys,
      float* __restrict__ pbary){
  int n = blockIdx.x*256 + threadIdx.x;
  if (n >= NPT) return;
  int b = n >> 16, pix = n & 65535;
  int y = pix >> 8, x = pix & 255;
  // scale[j] = sqrt(2/3)*6 / sqrt((j+1)(j+2)), as float32 (numpy f64 -> f32)
  const float sc0 = 3.4641016151377544f, sc1 = 2.0f, sc2 = 1.4142135623730951f,
              sc3 = 1.0954451150103321f, sc4 = 0.8944271909999159f;
  size_t ib = ((size_t)b*3) << 16;
  float f0 = ((float)x / 80.0f) * sc0;                      // xs / THETA_ALPHA
  float f1 = ((float)y / 80.0f) * sc1;                      // ys / THETA_ALPHA
  float f2 = (img[ib + pix]          / 13.0f) * sc2;        // R / THETA_BETA
  float f3 = (img[ib + 65536 + pix]  / 13.0f) * sc3;        // G
  float f4 = (img[ib + 131072 + pix] / 13.0f) * sc4;        // B
  // elevate: E rows [1,1,1,1,1],[-1,1,1,1,1],[0,-2,1,1,1],[0,0,-3,1,1],[0,0,0,-4,1],[0,0,0,0,-5]
  float E[6];
  {
    float s4 = f4;
    E[5] = -5.0f*f4;
    E[4] = -4.0f*f3 + s4;
    float s3 = f3 + s4;
    E[3] = -3.0f*f2 + s3;
    float s2 = f2 + s3;
    E[2] = -2.0f*f1 + s2;
    float s1 = f1 + s2;
    E[1] = -f0 + s1;
    E[0] =  f0 + s1;
  }
  float rem0[6], di[6]; int rk[6];
  float ssf = 0.f;
  #pragma unroll
  for (int i=0;i<6;i++){
    float v  = E[i] / 6.0f;
    float up = ceilf(v)*6.0f, dn = floorf(v)*6.0f;
    float r0 = (up - E[i] < E[i] - dn) ? up : dn;
    rem0[i] = r0; di[i] = E[i] - r0; ssf += r0;     // di from PRE-wrap rem0
  }
  int ssum = (int)rintf(ssf / 6.0f);                 // exact: rem0 are multiples of 6
  #pragma unroll
  for (int i=0;i<6;i++){
    int c = ssum;
    #pragma unroll
    for (int k=0;k<6;k++){
      if (k==i) continue;
      bool t = (k>i) ? (di[i] < di[k]) : (di[i] <= di[k]);
      c += t ? 1 : 0;
    }
    rk[i] = c;
  }
  #pragma unroll
  for (int i=0;i<6;i++){
    if      (rk[i] < 0){ rk[i] += 6; rem0[i] += 6.0f; }
    else if (rk[i] > 5){ rk[i] -= 6; rem0[i] -= 6.0f; }
  }
  // barycentric: bar[5-rk] += t; bar[6-rk] -= t  (unrolled to keep in registers)
  float bar[7] = {0,0,0,0,0,0,0};
  #pragma unroll
  for (int i=0;i<6;i++){
    float t = (E[i] - rem0[i]) / 6.0f;               // t from POST-wrap rem0
    #pragma unroll
    for (int j=0;j<7;j++){
      bar[j] += ((5-rk[i])==j) ? t : 0.0f;
      bar[j] -= ((6-rk[i])==j) ? t : 0.0f;
    }
  }
  float w0 = bar[0] + 1.0f + bar[6];
  int ri[5];
  #pragma unroll
  for (int i=0;i<5;i++) ri[i] = (int)rintf(rem0[i]);
  uint64_t bbit = ((uint64_t)b) << 60;
  #pragma unroll
  for (int r=0;r<6;r++){
    uint64_t key = bbit;
    #pragma unroll
    for (int i=0;i<5;i++){
      int k = ri[i] + r - ((rk[i] > 5-r) ? 6 : 0);
      key |= ((uint64_t)(uint32_t)(k + 2048)) << (12*i);
    }
    pkeys[n*6+r] = key;
    pbary[n*6+r] = (r==0) ? w0 : bar[r];
    uint32_t h = (uint32_t)hmix(key) & TMASK;
    for (uint32_t p = 0; p < TS; ++p){
      // cheap read first: skip CAS when slot already holds our key
      unsigned long long seen = hk[h];
      if (seen == (unsigned long long)key) break;
      if (seen == EMPTYK){
        unsigned long long prev = atomicCAS(&hk[h], EMPTYK, (unsigned long long)key);
        if (prev == EMPTYK || prev == (unsigned long long)key) break;
        // lost race to a different key: fall through and keep probing
      }
      h = (h + 1) & TMASK;
    }
  }
}

// K2: block-aggregated compaction — ONE counter atomic per block
__global__ __launch_bounds__(256) void k_compact(const unsigned long long* __restrict__ hk,
      int* __restrict__ sidx, unsigned long long* __restrict__ latkeys, int* __restrict__ counter){
  __shared__ int wtot[4];
  __shared__ int bbase;
  uint32_t s = blockIdx.x*256 + threadIdx.x;
  unsigned long long k = hk[s];
  bool occ = (k != EMPTYK);
  unsigned long long mask = __ballot(occ);
  int lane = threadIdx.x & 63, w = threadIdx.x >> 6;
  int pre = __popcll(mask & ((1ULL << lane) - 1ULL));
  if (lane == 0) wtot[w] = __popcll(mask);
  __syncthreads();
  if (threadIdx.x == 0){
    int s0 = 0;
    #pragma unroll
    for (int i=0;i<4;i++){ int t = wtot[i]; wtot[i] = s0; s0 += t; }
    bbase = s0 ? atomicAdd(counter, s0) : 0;
  }
  __syncthreads();
  if (occ){
    int i = bbase + wtot[w] + pre;
    sidx[s] = i;
    latkeys[i] = k;
  }
}

// K3: per (point,vertex) -> compact lattice index, + histogram of pairs per vertex
__global__ __launch_bounds__(256) void k_find(const unsigned long long* __restrict__ hk,
      const int* __restrict__ sidx, const unsigned long long* __restrict__ pkeys,
      int* __restrict__ pidx, int* __restrict__ cnt){
  int t = blockIdx.x*256 + threadIdx.x;
  if (t >= NV) return;
  int i = hlookup(hk, sidx, pkeys[t]);
  i = (i >= 0) ? i : 0;   // always found (inserted in K1)
  pidx[t] = i;
  atomicAdd(&cnt[i], 1);
}

// Scan stage 1: per-block (1024) exclusive scan of cnt -> off, block totals -> bsum
__global__ __launch_bounds__(1024) void k_scan1(const int* __restrict__ cnt,
      int* __restrict__ off, int* __restrict__ bsum){
  __shared__ int s[1024];
  int t = threadIdx.x;
  int i = blockIdx.x*1024 + t;
  int v = cnt[i];
  s[t] = v;
  __syncthreads();
  #pragma unroll
  for (int o=1;o<1024;o<<=1){
    int add = (t>=o) ? s[t-o] : 0;
    __syncthreads();
    s[t] += add;
    __syncthreads();
  }
  off[i] = s[t] - v;                 // exclusive within block
  if (t==1023) bsum[blockIdx.x] = s[t];
}

// Scan stage 2: exclusive scan of NBLK block sums (single block)
__global__ __launch_bounds__(1024) void k_scan2(int* __restrict__ bsum){
  __shared__ int s[1024];
  int t = threadIdx.x;
  int v = (t < NBLK) ? bsum[t] : 0;
  s[t] = v;
  __syncthreads();
  #pragma unroll
  for (int o=1;o<1024;o<<=1){
    int add = (t>=o) ? s[t-o] : 0;
    __syncthreads();
    s[t] += add;
    __syncthreads();
  }
  if (t < NBLK) bsum[t] = s[t] - v;
}

// Scan stage 3: add block offsets; also init cursor copy
__global__ __launch_bounds__(1024) void k_scan3(int* __restrict__ off,
      const int* __restrict__ bsum, int* __restrict__ cur){
  int i = blockIdx.x*1024 + threadIdx.x;
  int o = off[i] + bsum[blockIdx.x];
  off[i] = o;
  cur[i] = o;
}

// K4a: scatter pair ids into CSR pairlist (one int atomic per pair)
__global__ __launch_bounds__(256) void k_scatter(const int* __restrict__ pidx,
      int* __restrict__ cur, int* __restrict__ pairlist){
  int t = blockIdx.x*256 + threadIdx.x;
  if (t >= NV) return;
  int idx = pidx[t];
  int pos = atomicAdd(&cur[idx], 1);
  pairlist[pos] = t;
}

// K4b: gather-reduce splat — one thread per lattice point, no float atomics
__global__ __launch_bounds__(256) void k_splat2(const float* __restrict__ xin,
      const int* __restrict__ off, const int* __restrict__ cnt,
      const int* __restrict__ pairlist, const float* __restrict__ pbary,
      const int* __restrict__ counter, float* __restrict__ lat){
  int m = blockIdx.x*256 + threadIdx.x;
  if (m >= *counter) return;
  float acc[CC];
  #pragma unroll
  for (int c=0;c<CC;c++) acc[c] = 0.f;
  int c0 = off[m], k = cnt[m];
  for (int e=c0; e<c0+k; ++e){
    int t = pairlist[e];
    int n = t/6;
    float w = pbary[t];
    int b = n >> 16, pix = n & 65535;
    const float* xb = xin + (((size_t)b*CC) << 16) + pix;
    #pragma unroll
    for (int c=0;c<CC;c++) acc[c] = fmaf(w, xb[(size_t)c << 16], acc[c]);
  }
  float* dstp = lat + (size_t)m*CP;
  #pragma unroll
  for (int c=0;c<CC;c++) dstp[c] = acc[c];
  dstp[21] = 0.f; dstp[22] = 0.f; dstp[23] = 0.f;
}

// K5: one blur direction: dst[m] = src[m] + 0.5*(src[n1] + src[n2]), missing -> 0
__global__ __launch_bounds__(256) void k_blur(const unsigned long long* __restrict__ hk,
      const int* __restrict__ sidx, const unsigned long long* __restrict__ latkeys,
      const int* __restrict__ counter, const float* __restrict__ src, float* __restrict__ dst,
      unsigned long long delta){
  int m = blockIdx.x*256 + threadIdx.x;
  if (m >= *counter) return;
  uint64_t key = (uint64_t)latkeys[m];
  int i1 = hlookup(hk, sidx, key + (uint64_t)delta);
  int i2 = hlookup(hk, sidx, key - (uint64_t)delta);
  const float4* a = (const float4*)(src + (size_t)m*CP);
  const float4* u = (i1 >= 0) ? (const float4*)(src + (size_t)i1*CP) : nullptr;
  const float4* v = (i2 >= 0) ? (const float4*)(src + (size_t)i2*CP) : nullptr;
  float4* o = (float4*)(dst + (size_t)m*CP);
  #pragma unroll
  for (int q=0;q<CP/4;q++){
    float4 av = a[q];
    float4 uv = u ? u[q] : make_float4(0.f,0.f,0.f,0.f);
    float4 vv = v ? v[q] : make_float4(0.f,0.f,0.f,0.f);
    float4 r;
    r.x = av.x + 0.5f*(uv.x + vv.x);
    r.y = av.y + 0.5f*(uv.y + vv.y);
    r.z = av.z + 0.5f*(uv.z + vv.z);
    r.w = av.w + 0.5f*(uv.w + vv.w);
    o[q] = r;
  }
}

// K6: slice — out[b,c,y,x] = alpha * sum_r bary[r] * lat[idx[r]][c]
__global__ __launch_bounds__(256) void k_slice(const float* __restrict__ lat,
      const int* __restrict__ pidx, const float* __restrict__ pbary, float* __restrict__ out){
  int n = blockIdx.x*256 + threadIdx.x;
  if (n >= NPT) return;
  float acc[CC];
  #pragma unroll
  for (int c=0;c<CC;c++) acc[c] = 0.f;
  #pragma unroll
  for (int r=0;r<6;r++){
    int idx = pidx[n*6+r]; float w = pbary[n*6+r];
    const float* L = lat + (size_t)idx*CP;
    #pragma unroll
    for (int c=0;c<CC;c++) acc[c] = fmaf(w, L[c], acc[c]);
  }
  int b = n >> 16, pix = n & 65535;
  float* ob = out + (((size_t)b*CC) << 16) + pix;
  const float alpha = 0.9696969696969697f;  // 1/(1+2^-5) = 32/33
  #pragma unroll
  for (int c=0;c<CC;c++) ob[(size_t)c << 16] = alpha * acc[c];
}

extern "C" void kernel_launch(void* const* d_in, const int* in_sizes, int n_in,
                              void* d_out, int out_size, void* d_ws, size_t ws_size,
                              hipStream_t stream){
  const float* xin = (const float*)d_in[0];   // (2,21,256,256)
  const float* img = (const float*)d_in[1];   // (2,3,256,256)
  float* out = (float*)d_out;                 // (2,21,256,256)

  // workspace carve (each region 256B-aligned)
  char* p = (char*)d_ws;
  auto carve = [&](size_t bytes)->char*{
    char* r = p; p += (bytes + 255) & ~(size_t)255; return r;
  };
  unsigned long long* hk      = (unsigned long long*)carve((size_t)TS*8);   // 16.8 MB
  int*                sidx    = (int*)               carve((size_t)TS*4);   //  8.4 MB
  unsigned long long* latkeys = (unsigned long long*)carve((size_t)NV*8);   //  6.3 MB
  int*                counter = (int*)               carve(256);
  unsigned long long* pkeys   = (unsigned long long*)carve((size_t)NV*8);   //  6.3 MB
  int*                pidx    = (int*)               carve((size_t)NV*4);   //  3.1 MB
  float*              pbary   = (float*)             carve((size_t)NV*4);   //  3.1 MB
  int*                cnt     = (int*)               carve((size_t)NV*4);   //  3.1 MB
  int*                off     = (int*)               carve((size_t)NV*4);   //  3.1 MB
  int*                cur     = (int*)               carve((size_t)NV*4);   //  3.1 MB
  int*                plist   = (int*)               carve((size_t)NV*4);   //  3.1 MB
  int*                bsum    = (int*)               carve((size_t)NBLK*4); //  3 KB
  float*              latA    = (float*)             carve((size_t)NV*CP*4);// 75.5 MB
  float*              latB    = (float*)             carve((size_t)NV*CP*4);// 75.5 MB

  hipMemsetAsync(hk, 0xFF, (size_t)TS*8, stream);
  hipMemsetAsync(counter, 0, 256, stream);
  hipMemsetAsync(cnt, 0, (size_t)NV*4, stream);

  k_build  <<<NPT/256, 256, 0, stream>>>(img, hk, pkeys, pbary);
  k_compact<<<TS/256,  256, 0, stream>>>(hk, sidx, latkeys, counter);
  k_find   <<<NV/256,  256, 0, stream>>>(hk, sidx, pkeys, pidx, cnt);
  k_scan1  <<<NBLK,   1024, 0, stream>>>(cnt, off, bsum);
  k_scan2  <<<1,      1024, 0, stream>>>(bsum);
  k_scan3  <<<NBLK,   1024, 0, stream>>>(off, bsum, cur);
  k_scatter<<<NV/256,  256, 0, stream>>>(pidx, cur, plist);
  k_splat2 <<<NV/256,  256, 0, stream>>>(xin, off, cnt, plist, pbary, counter, latA);

  // blur deltas: off = ones(6), off[j] = -5; packed coords are fields i=0..4.
  // delta_j = sum_{i<5} 4096^i - 6*4096^j (j<5); j==5 only touches the unpacked coord.
  const long long S5 = (1LL<<48)+(1LL<<36)+(1LL<<24)+(1LL<<12)+1LL;
  float* src = latA; float* dst = latB;
  for (int j=0;j<6;j++){
    long long delta = (j<5) ? (S5 - (6LL << (12*j))) : S5;
    k_blur<<<NV/256, 256, 0, stream>>>(hk, sidx, latkeys, counter, src, dst,
                                       (unsigned long long)delta);
    float* tmp = src; src = dst; dst = tmp;
  }
  // after 6 swaps src == latA (final)
  k_slice<<<NPT/256, 256, 0, stream>>>(src, pidx, pbary, out);
}

// Round 4
// 761.872 us; speedup vs baseline: 2.3433x; 1.2125x over previous
//
#include <hip/hip_runtime.h>
#include <stdint.h>

// Problem constants (x: (2,21,256,256) f32, image: (2,3,256,256) f32, bilateral d=5)
#define BB   2
#define CC   21
#define CP   24              // padded channel stride (float4-aligned)
#define NPT  (BB*256*256)    // 131072 points
#define DP1  6
#define NV   (NPT*DP1)       // 786432 point-vertex pairs (max unique keys)
#define TS   (1u<<21)        // hash slots (max load 37.5%)
#define TMASK (TS-1)
#define EMPTYK 0xFFFFFFFFFFFFFFFFULL
#define NBLK (NV/1024)       // 768 scan blocks

__device__ __forceinline__ uint64_t hmix(uint64_t x){
  x ^= x >> 33; x *= 0xff51afd7ed558ccdULL;
  x ^= x >> 33; x *= 0xc4ceb9fe1a85ec53ULL;
  x ^= x >> 33; return x;
}

__device__ __forceinline__ int hlookup(const unsigned long long* __restrict__ hk,
                                       const int* __restrict__ sidx, uint64_t key){
  uint32_t h = (uint32_t)hmix(key) & TMASK;
  for (uint32_t p = 0; p < TS; ++p){
    unsigned long long k = hk[h];
    if (k == (unsigned long long)key) return sidx[h];
    if (k == EMPTYK) return -1;
    h = (h + 1) & TMASK;
  }
  return -1;
}

// K0: transpose x (NCHW) -> xt (row-per-pixel, 24-float padded rows)
__global__ __launch_bounds__(256) void k_tx(const float* __restrict__ xin,
      float* __restrict__ xt){
  int n = blockIdx.x*256 + threadIdx.x;
  if (n >= NPT) return;
  int b = n >> 16, pix = n & 65535;
  const float* xb = xin + (((size_t)b*CC) << 16) + pix;
  float v[CP];
  #pragma unroll
  for (int c=0;c<CC;c++) v[c] = xb[(size_t)c << 16];
  v[21]=0.f; v[22]=0.f; v[23]=0.f;
  float4* o = (float4*)(xt + (size_t)n*CP);
  #pragma unroll
  for (int q=0;q<6;q++) o[q] = make_float4(v[4*q], v[4*q+1], v[4*q+2], v[4*q+3]);
}

// K1: per-point lattice math + hash insert (key-only)
__global__ __launch_bounds__(256) void k_build(const float* __restrict__ img,
      unsigned long long* __restrict__ hk,
      unsigned long long* __restrict__ pkeys,
      float* __restrict__ pbary){
  int n = blockIdx.x*256 + threadIdx.x;
  if (n >= NPT) return;
  int b = n >> 16, pix = n & 65535;
  int y = pix >> 8, x = pix & 255;
  // scale[j] = sqrt(2/3)*6 / sqrt((j+1)(j+2)), as float32 (numpy f64 -> f32)
  const float sc0 = 3.4641016151377544f, sc1 = 2.0f, sc2 = 1.4142135623730951f,
              sc3 = 1.0954451150103321f, sc4 = 0.8944271909999159f;
  size_t ib = ((size_t)b*3) << 16;
  float f0 = ((float)x / 80.0f) * sc0;                      // xs / THETA_ALPHA
  float f1 = ((float)y / 80.0f) * sc1;                      // ys / THETA_ALPHA
  float f2 = (img[ib + pix]          / 13.0f) * sc2;        // R / THETA_BETA
  float f3 = (img[ib + 65536 + pix]  / 13.0f) * sc3;        // G
  float f4 = (img[ib + 131072 + pix] / 13.0f) * sc4;        // B
  // elevate: E rows [1,1,1,1,1],[-1,1,1,1,1],[0,-2,1,1,1],[0,0,-3,1,1],[0,0,0,-4,1],[0,0,0,0,-5]
  float E[6];
  {
    float s4 = f4;
    E[5] = -5.0f*f4;
    E[4] = -4.0f*f3 + s4;
    float s3 = f3 + s4;
    E[3] = -3.0f*f2 + s3;
    float s2 = f2 + s3;
    E[2] = -2.0f*f1 + s2;
    float s1 = f1 + s2;
    E[1] = -f0 + s1;
    E[0] =  f0 + s1;
  }
  float rem0[6], di[6]; int rk[6];
  float ssf = 0.f;
  #pragma unroll
  for (int i=0;i<6;i++){
    float v  = E[i] / 6.0f;
    float up = ceilf(v)*6.0f, dn = floorf(v)*6.0f;
    float r0 = (up - E[i] < E[i] - dn) ? up : dn;
    rem0[i] = r0; di[i] = E[i] - r0; ssf += r0;     // di from PRE-wrap rem0
  }
  int ssum = (int)rintf(ssf / 6.0f);                 // exact: rem0 are multiples of 6
  #pragma unroll
  for (int i=0;i<6;i++){
    int c = ssum;
    #pragma unroll
    for (int k=0;k<6;k++){
      if (k==i) continue;
      bool t = (k>i) ? (di[i] < di[k]) : (di[i] <= di[k]);
      c += t ? 1 : 0;
    }
    rk[i] = c;
  }
  #pragma unroll
  for (int i=0;i<6;i++){
    if      (rk[i] < 0){ rk[i] += 6; rem0[i] += 6.0f; }
    else if (rk[i] > 5){ rk[i] -= 6; rem0[i] -= 6.0f; }
  }
  // barycentric: bar[5-rk] += t; bar[6-rk] -= t  (unrolled to keep in registers)
  float bar[7] = {0,0,0,0,0,0,0};
  #pragma unroll
  for (int i=0;i<6;i++){
    float t = (E[i] - rem0[i]) / 6.0f;               // t from POST-wrap rem0
    #pragma unroll
    for (int j=0;j<7;j++){
      bar[j] += ((5-rk[i])==j) ? t : 0.0f;
      bar[j] -= ((6-rk[i])==j) ? t : 0.0f;
    }
  }
  float w0 = bar[0] + 1.0f + bar[6];
  int ri[5];
  #pragma unroll
  for (int i=0;i<5;i++) ri[i] = (int)rintf(rem0[i]);
  uint64_t bbit = ((uint64_t)b) << 60;
  #pragma unroll
  for (int r=0;r<6;r++){
    uint64_t key = bbit;
    #pragma unroll
    for (int i=0;i<5;i++){
      int k = ri[i] + r - ((rk[i] > 5-r) ? 6 : 0);
      key |= ((uint64_t)(uint32_t)(k + 2048)) << (12*i);
    }
    pkeys[n*6+r] = key;
    pbary[n*6+r] = (r==0) ? w0 : bar[r];
    uint32_t h = (uint32_t)hmix(key) & TMASK;
    for (uint32_t p = 0; p < TS; ++p){
      // cheap read first: skip CAS when slot already holds our key
      unsigned long long seen = hk[h];
      if (seen == (unsigned long long)key) break;
      if (seen == EMPTYK){
        unsigned long long prev = atomicCAS(&hk[h], EMPTYK, (unsigned long long)key);
        if (prev == EMPTYK || prev == (unsigned long long)key) break;
        // lost race to a different key: fall through and keep probing
      }
      h = (h + 1) & TMASK;
    }
  }
}

// K2: block-aggregated compaction — ONE counter atomic per block
__global__ __launch_bounds__(256) void k_compact(const unsigned long long* __restrict__ hk,
      int* __restrict__ sidx, unsigned long long* __restrict__ latkeys, int* __restrict__ counter){
  __shared__ int wtot[4];
  __shared__ int bbase;
  uint32_t s = blockIdx.x*256 + threadIdx.x;
  unsigned long long k = hk[s];
  bool occ = (k != EMPTYK);
  unsigned long long mask = __ballot(occ);
  int lane = threadIdx.x & 63, w = threadIdx.x >> 6;
  int pre = __popcll(mask & ((1ULL << lane) - 1ULL));
  if (lane == 0) wtot[w] = __popcll(mask);
  __syncthreads();
  if (threadIdx.x == 0){
    int s0 = 0;
    #pragma unroll
    for (int i=0;i<4;i++){ int t = wtot[i]; wtot[i] = s0; s0 += t; }
    bbase = s0 ? atomicAdd(counter, s0) : 0;
  }
  __syncthreads();
  if (occ){
    int i = bbase + wtot[w] + pre;
    sidx[s] = i;
    latkeys[i] = k;
  }
}

// K3: per (point,vertex) -> compact lattice index, + histogram of pairs per vertex
__global__ __launch_bounds__(256) void k_find(const unsigned long long* __restrict__ hk,
      const int* __restrict__ sidx, const unsigned long long* __restrict__ pkeys,
      int* __restrict__ pidx, int* __restrict__ cnt){
  int t = blockIdx.x*256 + threadIdx.x;
  if (t >= NV) return;
  int i = hlookup(hk, sidx, pkeys[t]);
  i = (i >= 0) ? i : 0;   // always found (inserted in K1)
  pidx[t] = i;
  atomicAdd(&cnt[i], 1);
}

// Scan stage 1: per-block (1024) exclusive scan of cnt -> off, block totals -> bsum
__global__ __launch_bounds__(1024) void k_scan1(const int* __restrict__ cnt,
      int* __restrict__ off, int* __restrict__ bsum){
  __shared__ int s[1024];
  int t = threadIdx.x;
  int i = blockIdx.x*1024 + t;
  int v = cnt[i];
  s[t] = v;
  __syncthreads();
  #pragma unroll
  for (int o=1;o<1024;o<<=1){
    int add = (t>=o) ? s[t-o] : 0;
    __syncthreads();
    s[t] += add;
    __syncthreads();
  }
  off[i] = s[t] - v;                 // exclusive within block
  if (t==1023) bsum[blockIdx.x] = s[t];
}

// Scan stage 2: exclusive scan of NBLK block sums (single block)
__global__ __launch_bounds__(1024) void k_scan2(int* __restrict__ bsum){
  __shared__ int s[1024];
  int t = threadIdx.x;
  int v = (t < NBLK) ? bsum[t] : 0;
  s[t] = v;
  __syncthreads();
  #pragma unroll
  for (int o=1;o<1024;o<<=1){
    int add = (t>=o) ? s[t-o] : 0;
    __syncthreads();
    s[t] += add;
    __syncthreads();
  }
  if (t < NBLK) bsum[t] = s[t] - v;
}

// Scan stage 3: add block offsets; also init cursor copy
__global__ __launch_bounds__(1024) void k_scan3(int* __restrict__ off,
      const int* __restrict__ bsum, int* __restrict__ cur){
  int i = blockIdx.x*1024 + threadIdx.x;
  int o = off[i] + bsum[blockIdx.x];
  off[i] = o;
  cur[i] = o;
}

// K4a: scatter {pixel id, weight} into CSR pairlist (one int atomic per pair)
__global__ __launch_bounds__(256) void k_scatter(const int* __restrict__ pidx,
      const float* __restrict__ pbary, int* __restrict__ cur, uint2* __restrict__ plist2){
  int t = blockIdx.x*256 + threadIdx.x;
  if (t >= NV) return;
  int idx = pidx[t];
  int pos = atomicAdd(&cur[idx], 1);
  plist2[pos] = make_uint2((uint32_t)(t/6), __float_as_uint(pbary[t]));
}

// K4b: gather-reduce splat — one thread per lattice point, contiguous 96B row gathers
__global__ __launch_bounds__(256) void k_splat2(const float* __restrict__ xt,
      const int* __restrict__ off, const int* __restrict__ cnt,
      const uint2* __restrict__ plist2, const int* __restrict__ counter,
      float* __restrict__ lat){
  int m = blockIdx.x*256 + threadIdx.x;
  if (m >= *counter) return;
  float4 acc[6];
  #pragma unroll
  for (int q=0;q<6;q++) acc[q] = make_float4(0.f,0.f,0.f,0.f);
  int c0 = off[m], k = cnt[m];
  for (int e=c0; e<c0+k; ++e){
    uint2 pv = plist2[e];
    float w = __uint_as_float(pv.y);
    const float4* xr = (const float4*)(xt + (size_t)pv.x*CP);
    #pragma unroll
    for (int q=0;q<6;q++){
      float4 v = xr[q];
      acc[q].x = fmaf(w, v.x, acc[q].x);
      acc[q].y = fmaf(w, v.y, acc[q].y);
      acc[q].z = fmaf(w, v.z, acc[q].z);
      acc[q].w = fmaf(w, v.w, acc[q].w);
    }
  }
  float4* dstp = (float4*)(lat + (size_t)m*CP);
  #pragma unroll
  for (int q=0;q<6;q++) dstp[q] = acc[q];   // pads stay 0 (xt pads are 0)
}

// K5: one blur direction: dst[m] = src[m] + 0.5*(src[n1] + src[n2]), missing -> 0
__global__ __launch_bounds__(256) void k_blur(const unsigned long long* __restrict__ hk,
      const int* __restrict__ sidx, const unsigned long long* __restrict__ latkeys,
      const int* __restrict__ counter, const float* __restrict__ src, float* __restrict__ dst,
      unsigned long long delta){
  int m = blockIdx.x*256 + threadIdx.x;
  if (m >= *counter) return;
  uint64_t key = (uint64_t)latkeys[m];
  int i1 = hlookup(hk, sidx, key + (uint64_t)delta);
  int i2 = hlookup(hk, sidx, key - (uint64_t)delta);
  const float4* a = (const float4*)(src + (size_t)m*CP);
  const float4* u = (i1 >= 0) ? (const float4*)(src + (size_t)i1*CP) : nullptr;
  const float4* v = (i2 >= 0) ? (const float4*)(src + (size_t)i2*CP) : nullptr;
  float4* o = (float4*)(dst + (size_t)m*CP);
  #pragma unroll
  for (int q=0;q<CP/4;q++){
    float4 av = a[q];
    float4 uv = u ? u[q] : make_float4(0.f,0.f,0.f,0.f);
    float4 vv = v ? v[q] : make_float4(0.f,0.f,0.f,0.f);
    float4 r;
    r.x = av.x + 0.5f*(uv.x + vv.x);
    r.y = av.y + 0.5f*(uv.y + vv.y);
    r.z = av.z + 0.5f*(uv.z + vv.z);
    r.w = av.w + 0.5f*(uv.w + vv.w);
    o[q] = r;
  }
}

// K6: slice — out[b,c,y,x] = alpha * sum_r bary[r] * lat[idx[r]][c]
__global__ __launch_bounds__(256) void k_slice(const float* __restrict__ lat,
      const int* __restrict__ pidx, const float* __restrict__ pbary, float* __restrict__ out){
  int n = blockIdx.x*256 + threadIdx.x;
  if (n >= NPT) return;
  float acc[CC];
  #pragma unroll
  for (int c=0;c<CC;c++) acc[c] = 0.f;
  #pragma unroll
  for (int r=0;r<6;r++){
    int idx = pidx[n*6+r]; float w = pbary[n*6+r];
    const float* L = lat + (size_t)idx*CP;
    #pragma unroll
    for (int c=0;c<CC;c++) acc[c] = fmaf(w, L[c], acc[c]);
  }
  int b = n >> 16, pix = n & 65535;
  float* ob = out + (((size_t)b*CC) << 16) + pix;
  const float alpha = 0.9696969696969697f;  // 1/(1+2^-5) = 32/33
  #pragma unroll
  for (int c=0;c<CC;c++) ob[(size_t)c << 16] = alpha * acc[c];
}

extern "C" void kernel_launch(void* const* d_in, const int* in_sizes, int n_in,
                              void* d_out, int out_size, void* d_ws, size_t ws_size,
                              hipStream_t stream){
  const float* xin = (const float*)d_in[0];   // (2,21,256,256)
  const float* img = (const float*)d_in[1];   // (2,3,256,256)
  float* out = (float*)d_out;                 // (2,21,256,256)

  // workspace carve (each region 256B-aligned)
  char* p = (char*)d_ws;
  auto carve = [&](size_t bytes)->char*{
    char* r = p; p += (bytes + 255) & ~(size_t)255; return r;
  };
  unsigned long long* hk      = (unsigned long long*)carve((size_t)TS*8);   // 16.8 MB
  int*                sidx    = (int*)               carve((size_t)TS*4);   //  8.4 MB
  unsigned long long* latkeys = (unsigned long long*)carve((size_t)NV*8);   //  6.3 MB
  int*                counter = (int*)               carve(256);
  unsigned long long* pkeys   = (unsigned long long*)carve((size_t)NV*8);   //  6.3 MB
  int*                pidx    = (int*)               carve((size_t)NV*4);   //  3.1 MB
  float*              pbary   = (float*)             carve((size_t)NV*4);   //  3.1 MB
  int*                cnt     = (int*)               carve((size_t)NV*4);   //  3.1 MB
  int*                off     = (int*)               carve((size_t)NV*4);   //  3.1 MB
  int*                cur     = (int*)               carve((size_t)NV*4);   //  3.1 MB
  int*                bsum    = (int*)               carve((size_t)NBLK*4); //  3 KB
  float*              latA    = (float*)             carve((size_t)NV*CP*4);// 75.5 MB
  float*              latB    = (float*)             carve((size_t)NV*CP*4);// 75.5 MB

  // aliases (non-overlapping liveness):
  //   xt     lives in latB[0 .. NPT*CP)  — dead before blur j=0 writes latB
  //   plist2 reuses pkeys                — pkeys dead after k_find
  float* xt      = latB;
  uint2* plist2  = (uint2*)pkeys;

  hipMemsetAsync(hk, 0xFF, (size_t)TS*8, stream);
  hipMemsetAsync(counter, 0, 256, stream);
  hipMemsetAsync(cnt, 0, (size_t)NV*4, stream);

  k_tx     <<<NPT/256, 256, 0, stream>>>(xin, xt);
  k_build  <<<NPT/256, 256, 0, stream>>>(img, hk, pkeys, pbary);
  k_compact<<<TS/256,  256, 0, stream>>>(hk, sidx, latkeys, counter);
  k_find   <<<NV/256,  256, 0, stream>>>(hk, sidx, pkeys, pidx, cnt);
  k_scan1  <<<NBLK,   1024, 0, stream>>>(cnt, off, bsum);
  k_scan2  <<<1,      1024, 0, stream>>>(bsum);
  k_scan3  <<<NBLK,   1024, 0, stream>>>(off, bsum, cur);
  k_scatter<<<NV/256,  256, 0, stream>>>(pidx, pbary, cur, plist2);
  k_splat2 <<<NV/256,  256, 0, stream>>>(xt, off, cnt, plist2, counter, latA);

  // blur deltas: off = ones(6), off[j] = -5; packed coords are fields i=0..4.
  // delta_j = sum_{i<5} 4096^i - 6*4096^j (j<5); j==5 only touches the unpacked coord.
  const long long S5 = (1LL<<48)+(1LL<<36)+(1LL<<24)+(1LL<<12)+1LL;
  float* src = latA; float* dst = latB;
  for (int j=0;j<6;j++){
    long long delta = (j<5) ? (S5 - (6LL << (12*j))) : S5;
    k_blur<<<NV/256, 256, 0, stream>>>(hk, sidx, latkeys, counter, src, dst,
                                       (unsigned long long)delta);
    float* tmp = src; src = dst; dst = tmp;
  }
  // after 6 swaps src == latA (final)
  k_slice<<<NPT/256, 256, 0, stream>>>(src, pidx, pbary, out);
}

// Round 5
// 680.426 us; speedup vs baseline: 2.6238x; 1.1197x over previous
//
#include <hip/hip_runtime.h>
#include <stdint.h>

// Problem constants (x: (2,21,256,256) f32, image: (2,3,256,256) f32, bilateral d=5)
#define BB   2
#define CC   21
#define CP   24              // padded channel stride (float4-aligned)
#define NPT  (BB*256*256)    // 131072 points
#define DP1  6
#define NV   (NPT*DP1)       // 786432 point-vertex pairs (max unique keys)
#define TS   (1u<<21)        // hash slots (max load 37.5%)
#define TMASK (TS-1)
#define EMPTYK 0xFFFFFFFFFFFFFFFFULL
#define NBLK (NV/1024)       // 768 scan blocks (pair-count scan)
#define CB   2048            // compaction blocks (TS/1024)

__device__ __forceinline__ uint64_t hmix(uint64_t x){
  x ^= x >> 33; x *= 0xff51afd7ed558ccdULL;
  x ^= x >> 33; x *= 0xc4ceb9fe1a85ec53ULL;
  x ^= x >> 33; return x;
}

__device__ __forceinline__ int hlookup(const unsigned long long* __restrict__ hk,
                                       const int* __restrict__ sidx, uint64_t key){
  uint32_t h = (uint32_t)hmix(key) & TMASK;
  for (uint32_t p = 0; p < TS; ++p){
    unsigned long long k = hk[h];
    if (k == (unsigned long long)key) return sidx[h];
    if (k == EMPTYK) return -1;
    h = (h + 1) & TMASK;
  }
  return -1;
}

// K0: transpose x (NCHW) -> xt (row-per-pixel, 24-float padded rows)
__global__ __launch_bounds__(256) void k_tx(const float* __restrict__ xin,
      float* __restrict__ xt){
  int n = blockIdx.x*256 + threadIdx.x;
  if (n >= NPT) return;
  int b = n >> 16, pix = n & 65535;
  const float* xb = xin + (((size_t)b*CC) << 16) + pix;
  float v[CP];
  #pragma unroll
  for (int c=0;c<CC;c++) v[c] = xb[(size_t)c << 16];
  v[21]=0.f; v[22]=0.f; v[23]=0.f;
  float4* o = (float4*)(xt + (size_t)n*CP);
  #pragma unroll
  for (int q=0;q<6;q++) o[q] = make_float4(v[4*q], v[4*q+1], v[4*q+2], v[4*q+3]);
}

// K1: per-point lattice math + hash insert (key-only)
__global__ __launch_bounds__(256) void k_build(const float* __restrict__ img,
      unsigned long long* __restrict__ hk,
      unsigned long long* __restrict__ pkeys,
      float* __restrict__ pbary){
  int n = blockIdx.x*256 + threadIdx.x;
  if (n >= NPT) return;
  int b = n >> 16, pix = n & 65535;
  int y = pix >> 8, x = pix & 255;
  // scale[j] = sqrt(2/3)*6 / sqrt((j+1)(j+2)), as float32 (numpy f64 -> f32)
  const float sc0 = 3.4641016151377544f, sc1 = 2.0f, sc2 = 1.4142135623730951f,
              sc3 = 1.0954451150103321f, sc4 = 0.8944271909999159f;
  size_t ib = ((size_t)b*3) << 16;
  float f0 = ((float)x / 80.0f) * sc0;                      // xs / THETA_ALPHA
  float f1 = ((float)y / 80.0f) * sc1;                      // ys / THETA_ALPHA
  float f2 = (img[ib + pix]          / 13.0f) * sc2;        // R / THETA_BETA
  float f3 = (img[ib + 65536 + pix]  / 13.0f) * sc3;        // G
  float f4 = (img[ib + 131072 + pix] / 13.0f) * sc4;        // B
  // elevate: E rows [1,1,1,1,1],[-1,1,1,1,1],[0,-2,1,1,1],[0,0,-3,1,1],[0,0,0,-4,1],[0,0,0,0,-5]
  float E[6];
  {
    float s4 = f4;
    E[5] = -5.0f*f4;
    E[4] = -4.0f*f3 + s4;
    float s3 = f3 + s4;
    E[3] = -3.0f*f2 + s3;
    float s2 = f2 + s3;
    E[2] = -2.0f*f1 + s2;
    float s1 = f1 + s2;
    E[1] = -f0 + s1;
    E[0] =  f0 + s1;
  }
  float rem0[6], di[6]; int rk[6];
  float ssf = 0.f;
  #pragma unroll
  for (int i=0;i<6;i++){
    float v  = E[i] / 6.0f;
    float up = ceilf(v)*6.0f, dn = floorf(v)*6.0f;
    float r0 = (up - E[i] < E[i] - dn) ? up : dn;
    rem0[i] = r0; di[i] = E[i] - r0; ssf += r0;     // di from PRE-wrap rem0
  }
  int ssum = (int)rintf(ssf / 6.0f);                 // exact: rem0 are multiples of 6
  #pragma unroll
  for (int i=0;i<6;i++){
    int c = ssum;
    #pragma unroll
    for (int k=0;k<6;k++){
      if (k==i) continue;
      bool t = (k>i) ? (di[i] < di[k]) : (di[i] <= di[k]);
      c += t ? 1 : 0;
    }
    rk[i] = c;
  }
  #pragma unroll
  for (int i=0;i<6;i++){
    if      (rk[i] < 0){ rk[i] += 6; rem0[i] += 6.0f; }
    else if (rk[i] > 5){ rk[i] -= 6; rem0[i] -= 6.0f; }
  }
  // barycentric: bar[5-rk] += t; bar[6-rk] -= t  (unrolled to keep in registers)
  float bar[7] = {0,0,0,0,0,0,0};
  #pragma unroll
  for (int i=0;i<6;i++){
    float t = (E[i] - rem0[i]) / 6.0f;               // t from POST-wrap rem0
    #pragma unroll
    for (int j=0;j<7;j++){
      bar[j] += ((5-rk[i])==j) ? t : 0.0f;
      bar[j] -= ((6-rk[i])==j) ? t : 0.0f;
    }
  }
  float w0 = bar[0] + 1.0f + bar[6];
  int ri[5];
  #pragma unroll
  for (int i=0;i<5;i++) ri[i] = (int)rintf(rem0[i]);
  uint64_t bbit = ((uint64_t)b) << 60;
  #pragma unroll
  for (int r=0;r<6;r++){
    uint64_t key = bbit;
    #pragma unroll
    for (int i=0;i<5;i++){
      int k = ri[i] + r - ((rk[i] > 5-r) ? 6 : 0);
      key |= ((uint64_t)(uint32_t)(k + 2048)) << (12*i);
    }
    pkeys[n*6+r] = key;
    pbary[n*6+r] = (r==0) ? w0 : bar[r];
    uint32_t h = (uint32_t)hmix(key) & TMASK;
    for (uint32_t p = 0; p < TS; ++p){
      // cheap read first: skip CAS when slot already holds our key
      unsigned long long seen = hk[h];
      if (seen == (unsigned long long)key) break;
      if (seen == EMPTYK){
        unsigned long long prev = atomicCAS(&hk[h], EMPTYK, (unsigned long long)key);
        if (prev == EMPTYK || prev == (unsigned long long)key) break;
        // lost race to a different key: fall through and keep probing
      }
      h = (h + 1) & TMASK;
    }
  }
}

// K2a: per-block occupancy count (no atomics)
__global__ __launch_bounds__(1024) void k_cpt1(const unsigned long long* __restrict__ hk,
      int* __restrict__ bcnt){
  __shared__ int wtot[16];
  uint32_t s = blockIdx.x*1024 + threadIdx.x;
  bool occ = (hk[s] != EMPTYK);
  unsigned long long mask = __ballot(occ);
  int lane = threadIdx.x & 63, w = threadIdx.x >> 6;
  if (lane == 0) wtot[w] = __popcll(mask);
  __syncthreads();
  if (threadIdx.x == 0){
    int s0 = 0;
    #pragma unroll
    for (int i=0;i<16;i++) s0 += wtot[i];
    bcnt[blockIdx.x] = s0;
  }
}

// K2b: single-block exclusive scan of CB block counts; writes total -> counter[0]
__global__ __launch_bounds__(1024) void k_scan_small(const int* __restrict__ bcnt,
      int* __restrict__ boff, int* __restrict__ counter){
  __shared__ int s[1024];
  __shared__ int carry;
  if (threadIdx.x == 0) carry = 0;
  __syncthreads();
  for (int base = 0; base < CB; base += 1024){
    int t = threadIdx.x;
    int v = bcnt[base + t];
    s[t] = v;
    __syncthreads();
    #pragma unroll
    for (int o=1;o<1024;o<<=1){
      int add = (t>=o) ? s[t-o] : 0;
      __syncthreads();
      s[t] += add;
      __syncthreads();
    }
    boff[base + t] = carry + s[t] - v;
    __syncthreads();
    if (t == 1023) carry += s[t];
    __syncthreads();
  }
  if (threadIdx.x == 0) counter[0] = carry;
}

// K2c: write compact indices using scanned block bases (deterministic, no atomics)
__global__ __launch_bounds__(1024) void k_cpt2(const unsigned long long* __restrict__ hk,
      const int* __restrict__ boff, int* __restrict__ sidx,
      unsigned long long* __restrict__ latkeys){
  __shared__ int wtot[16];
  uint32_t s = blockIdx.x*1024 + threadIdx.x;
  unsigned long long k = hk[s];
  bool occ = (k != EMPTYK);
  unsigned long long mask = __ballot(occ);
  int lane = threadIdx.x & 63, w = threadIdx.x >> 6;
  int pre = __popcll(mask & ((1ULL << lane) - 1ULL));
  if (lane == 0) wtot[w] = __popcll(mask);
  __syncthreads();
  if (threadIdx.x == 0){
    int s0 = 0;
    #pragma unroll
    for (int i=0;i<16;i++){ int t = wtot[i]; wtot[i] = s0; s0 += t; }
  }
  __syncthreads();
  if (occ){
    int i = boff[blockIdx.x] + wtot[w] + pre;
    sidx[s] = i;
    latkeys[i] = k;
  }
}

// K3: per (point,vertex) -> compact lattice index, + histogram of pairs per vertex
__global__ __launch_bounds__(256) void k_find(const unsigned long long* __restrict__ hk,
      const int* __restrict__ sidx, const unsigned long long* __restrict__ pkeys,
      int* __restrict__ pidx, int* __restrict__ cnt){
  int t = blockIdx.x*256 + threadIdx.x;
  if (t >= NV) return;
  int i = hlookup(hk, sidx, pkeys[t]);
  i = (i >= 0) ? i : 0;   // always found (inserted in K1)
  pidx[t] = i;
  atomicAdd(&cnt[i], 1);
}

// Scan stage 1: per-block (1024) exclusive scan of cnt -> off, block totals -> bsum
__global__ __launch_bounds__(1024) void k_scan1(const int* __restrict__ cnt,
      int* __restrict__ off, int* __restrict__ bsum){
  __shared__ int s[1024];
  int t = threadIdx.x;
  int i = blockIdx.x*1024 + t;
  int v = cnt[i];
  s[t] = v;
  __syncthreads();
  #pragma unroll
  for (int o=1;o<1024;o<<=1){
    int add = (t>=o) ? s[t-o] : 0;
    __syncthreads();
    s[t] += add;
    __syncthreads();
  }
  off[i] = s[t] - v;                 // exclusive within block
  if (t==1023) bsum[blockIdx.x] = s[t];
}

// Scan stage 2: exclusive scan of NBLK block sums (single block)
__global__ __launch_bounds__(1024) void k_scan2(int* __restrict__ bsum){
  __shared__ int s[1024];
  int t = threadIdx.x;
  int v = (t < NBLK) ? bsum[t] : 0;
  s[t] = v;
  __syncthreads();
  #pragma unroll
  for (int o=1;o<1024;o<<=1){
    int add = (t>=o) ? s[t-o] : 0;
    __syncthreads();
    s[t] += add;
    __syncthreads();
  }
  if (t < NBLK) bsum[t] = s[t] - v;
}

// Scan stage 3: add block offsets; also init cursor copy
__global__ __launch_bounds__(1024) void k_scan3(int* __restrict__ off,
      const int* __restrict__ bsum, int* __restrict__ cur){
  int i = blockIdx.x*1024 + threadIdx.x;
  int o = off[i] + bsum[blockIdx.x];
  off[i] = o;
  cur[i] = o;
}

// K4a: scatter {pixel id, weight} into CSR pairlist (one int atomic per pair)
__global__ __launch_bounds__(256) void k_scatter(const int* __restrict__ pidx,
      const float* __restrict__ pbary, int* __restrict__ cur, uint2* __restrict__ plist2){
  int t = blockIdx.x*256 + threadIdx.x;
  if (t >= NV) return;
  int idx = pidx[t];
  int pos = atomicAdd(&cur[idx], 1);
  plist2[pos] = make_uint2((uint32_t)(t/6), __float_as_uint(pbary[t]));
}

// K4b: gather-reduce splat — one thread per lattice point, contiguous 96B row gathers
__global__ __launch_bounds__(256) void k_splat2(const float* __restrict__ xt,
      const int* __restrict__ off, const int* __restrict__ cnt,
      const uint2* __restrict__ plist2, const int* __restrict__ counter,
      float* __restrict__ lat){
  int m = blockIdx.x*256 + threadIdx.x;
  if (m >= *counter) return;
  float4 acc[6];
  #pragma unroll
  for (int q=0;q<6;q++) acc[q] = make_float4(0.f,0.f,0.f,0.f);
  int c0 = off[m], k = cnt[m];
  for (int e=c0; e<c0+k; ++e){
    uint2 pv = plist2[e];
    float w = __uint_as_float(pv.y);
    const float4* xr = (const float4*)(xt + (size_t)pv.x*CP);
    #pragma unroll
    for (int q=0;q<6;q++){
      float4 v = xr[q];
      acc[q].x = fmaf(w, v.x, acc[q].x);
      acc[q].y = fmaf(w, v.y, acc[q].y);
      acc[q].z = fmaf(w, v.z, acc[q].z);
      acc[q].w = fmaf(w, v.w, acc[q].w);
    }
  }
  float4* dstp = (float4*)(lat + (size_t)m*CP);
  #pragma unroll
  for (int q=0;q<6;q++) dstp[q] = acc[q];   // pads stay 0 (xt pads are 0)
}

// K5: one blur direction: dst[m] = src[m] + 0.5*(src[n1] + src[n2]), missing -> 0
__global__ __launch_bounds__(256) void k_blur(const unsigned long long* __restrict__ hk,
      const int* __restrict__ sidx, const unsigned long long* __restrict__ latkeys,
      const int* __restrict__ counter, const float* __restrict__ src, float* __restrict__ dst,
      unsigned long long delta){
  int m = blockIdx.x*256 + threadIdx.x;
  if (m >= *counter) return;
  uint64_t key = (uint64_t)latkeys[m];
  int i1 = hlookup(hk, sidx, key + (uint64_t)delta);
  int i2 = hlookup(hk, sidx, key - (uint64_t)delta);
  const float4* a = (const float4*)(src + (size_t)m*CP);
  const float4* u = (i1 >= 0) ? (const float4*)(src + (size_t)i1*CP) : nullptr;
  const float4* v = (i2 >= 0) ? (const float4*)(src + (size_t)i2*CP) : nullptr;
  float4* o = (float4*)(dst + (size_t)m*CP);
  #pragma unroll
  for (int q=0;q<CP/4;q++){
    float4 av = a[q];
    float4 uv = u ? u[q] : make_float4(0.f,0.f,0.f,0.f);
    float4 vv = v ? v[q] : make_float4(0.f,0.f,0.f,0.f);
    float4 r;
    r.x = av.x + 0.5f*(uv.x + vv.x);
    r.y = av.y + 0.5f*(uv.y + vv.y);
    r.z = av.z + 0.5f*(uv.z + vv.z);
    r.w = av.w + 0.5f*(uv.w + vv.w);
    o[q] = r;
  }
}

// K6: slice — out[b,c,y,x] = alpha * sum_r bary[r] * lat[idx[r]][c]
__global__ __launch_bounds__(256) void k_slice(const float* __restrict__ lat,
      const int* __restrict__ pidx, const float* __restrict__ pbary, float* __restrict__ out){
  int n = blockIdx.x*256 + threadIdx.x;
  if (n >= NPT) return;
  float acc[CC];
  #pragma unroll
  for (int c=0;c<CC;c++) acc[c] = 0.f;
  #pragma unroll
  for (int r=0;r<6;r++){
    int idx = pidx[n*6+r]; float w = pbary[n*6+r];
    const float* L = lat + (size_t)idx*CP;
    #pragma unroll
    for (int c=0;c<CC;c++) acc[c] = fmaf(w, L[c], acc[c]);
  }
  int b = n >> 16, pix = n & 65535;
  float* ob = out + (((size_t)b*CC) << 16) + pix;
  const float alpha = 0.9696969696969697f;  // 1/(1+2^-5) = 32/33
  #pragma unroll
  for (int c=0;c<CC;c++) ob[(size_t)c << 16] = alpha * acc[c];
}

extern "C" void kernel_launch(void* const* d_in, const int* in_sizes, int n_in,
                              void* d_out, int out_size, void* d_ws, size_t ws_size,
                              hipStream_t stream){
  const float* xin = (const float*)d_in[0];   // (2,21,256,256)
  const float* img = (const float*)d_in[1];   // (2,3,256,256)
  float* out = (float*)d_out;                 // (2,21,256,256)

  // workspace carve (each region 256B-aligned)
  char* p = (char*)d_ws;
  auto carve = [&](size_t bytes)->char*{
    char* r = p; p += (bytes + 255) & ~(size_t)255; return r;
  };
  unsigned long long* hk      = (unsigned long long*)carve((size_t)TS*8);   // 16.8 MB
  int*                sidx    = (int*)               carve((size_t)TS*4);   //  8.4 MB
  unsigned long long* latkeys = (unsigned long long*)carve((size_t)NV*8);   //  6.3 MB
  int*                counter = (int*)               carve(256);
  unsigned long long* pkeys   = (unsigned long long*)carve((size_t)NV*8);   //  6.3 MB
  int*                pidx    = (int*)               carve((size_t)NV*4);   //  3.1 MB
  float*              pbary   = (float*)             carve((size_t)NV*4);   //  3.1 MB
  int*                cnt     = (int*)               carve((size_t)NV*4);   //  3.1 MB
  int*                off     = (int*)               carve((size_t)NV*4);   //  3.1 MB
  int*                cur     = (int*)               carve((size_t)NV*4);   //  3.1 MB
  int*                bsum    = (int*)               carve((size_t)NBLK*4); //  3 KB
  int*                bcnt    = (int*)               carve((size_t)CB*4);   //  8 KB
  int*                boff    = (int*)               carve((size_t)CB*4);   //  8 KB
  float*              latA    = (float*)             carve((size_t)NV*CP*4);// 75.5 MB
  float*              latB    = (float*)             carve((size_t)NV*CP*4);// 75.5 MB

  // aliases (non-overlapping liveness):
  //   xt     lives in latB[0 .. NPT*CP)  — dead before blur j=0 writes latB
  //   plist2 reuses pkeys                — pkeys dead after k_find
  float* xt      = latB;
  uint2* plist2  = (uint2*)pkeys;

  hipMemsetAsync(hk, 0xFF, (size_t)TS*8, stream);
  hipMemsetAsync(cnt, 0, (size_t)NV*4, stream);

  k_tx        <<<NPT/256, 256, 0, stream>>>(xin, xt);
  k_build     <<<NPT/256, 256, 0, stream>>>(img, hk, pkeys, pbary);
  k_cpt1      <<<CB,     1024, 0, stream>>>(hk, bcnt);
  k_scan_small<<<1,      1024, 0, stream>>>(bcnt, boff, counter);
  k_cpt2      <<<CB,     1024, 0, stream>>>(hk, boff, sidx, latkeys);
  k_find      <<<NV/256,  256, 0, stream>>>(hk, sidx, pkeys, pidx, cnt);
  k_scan1     <<<NBLK,   1024, 0, stream>>>(cnt, off, bsum);
  k_scan2     <<<1,      1024, 0, stream>>>(bsum);
  k_scan3     <<<NBLK,   1024, 0, stream>>>(off, bsum, cur);
  k_scatter   <<<NV/256,  256, 0, stream>>>(pidx, pbary, cur, plist2);
  k_splat2    <<<NV/256,  256, 0, stream>>>(xt, off, cnt, plist2, counter, latA);

  // blur deltas: off = ones(6), off[j] = -5; packed coords are fields i=0..4.
  // delta_j = sum_{i<5} 4096^i - 6*4096^j (j<5); j==5 only touches the unpacked coord.
  const long long S5 = (1LL<<48)+(1LL<<36)+(1LL<<24)+(1LL<<12)+1LL;
  float* src = latA; float* dst = latB;
  for (int j=0;j<6;j++){
    long long delta = (j<5) ? (S5 - (6LL << (12*j))) : S5;
    k_blur<<<NV/256, 256, 0, stream>>>(hk, sidx, latkeys, counter, src, dst,
                                       (unsigned long long)delta);
    float* tmp = src; src = dst; dst = tmp;
  }
  // after 6 swaps src == latA (final)
  k_slice<<<NPT/256, 256, 0, stream>>>(src, pidx, pbary, out);
}